// Round 1
// baseline (1452.413 us; speedup 1.0000x reference)
//
#include <hip/hip_runtime.h>

#define NN 50000
#define NE 1600000
#define D 128
#define RPB 16  // rows per block in the GEMM epilogue

// ---------------- degree: deg[src[e]] += 1 ----------------
__global__ void deg_kernel(const int* __restrict__ src, float* __restrict__ deg, int E) {
    int i = blockIdx.x * blockDim.x + threadIdx.x;
    int stride = gridDim.x * blockDim.x;
    for (int e = i; e < E; e += stride) {
        unsafeAtomicAdd(&deg[src[e]], 1.0f);
    }
}

// ---------------- inv_norm[i] = rsqrt(deg[i]+1), in place ----------------
__global__ void inv_kernel(float* __restrict__ deg, int n) {
    int i = blockIdx.x * blockDim.x + threadIdx.x;
    if (i < n) deg[i] = rsqrtf(deg[i] + 1.0f);
}

// ---------------- Wt[k][c] = W[c][k] ----------------
__global__ void transpose_w(const float* __restrict__ W, float* __restrict__ Wt) {
    int i = blockIdx.x * blockDim.x + threadIdx.x;  // 16384 total
    int c = i >> 7;
    int k = i & 127;
    Wt[k * D + c] = W[i];
}

// ---------------- agg[i][:] = x[i][:] * inv[i]  (self loop, pre-scaled) ----------------
__global__ void init_agg(const float* __restrict__ x, const float* __restrict__ inv,
                         float* __restrict__ agg, int n4) {
    // n4 = NN * 32 float4 elements
    int i = blockIdx.x * blockDim.x + threadIdx.x;
    int stride = gridDim.x * blockDim.x;
    for (; i < n4; i += stride) {
        int row = i >> 5;  // 32 float4 per row
        float w = inv[row];
        float4 v = ((const float4*)x)[i];
        v.x *= w; v.y *= w; v.z *= w; v.w *= w;
        ((float4*)agg)[i] = v;
    }
}

// ---------------- scatter: agg[dst[e]][:] += x[src[e]][:] * inv[src[e]] ----------------
// one wave (64 lanes) per edge; each lane handles 2 columns (float2)
__global__ void scatter_kernel(const float* __restrict__ x, const int* __restrict__ ei,
                               const float* __restrict__ inv, float* agg, int E) {
    int gtid = blockIdx.x * blockDim.x + threadIdx.x;
    int wave = gtid >> 6;
    int lane = threadIdx.x & 63;
    int nwaves = (gridDim.x * blockDim.x) >> 6;
    for (int e = wave; e < E; e += nwaves) {
        int s = ei[e];
        int d = ei[NE + e];
        float w = inv[s];
        const float2 v = *(const float2*)(x + (size_t)s * D + lane * 2);
        float* p = agg + (size_t)d * D + lane * 2;
        unsafeAtomicAdd(p,     v.x * w);
        unsafeAtomicAdd(p + 1, v.y * w);
    }
}

// ---------------- out[r][c] = (agg[r][:] * inv[r]) . Wt[:][c] + b[c]  (in-place in io) ----------------
__global__ __launch_bounds__(256) void gemm_kernel(float* io, const float* __restrict__ inv,
                                                   const float* __restrict__ Wt,
                                                   const float* __restrict__ b) {
    __shared__ float h[RPB][D];
    int r0 = blockIdx.x * RPB;

    // stage + scale 16 rows into LDS (512 float4, 2 per thread)
    const float4* src4 = (const float4*)(io + (size_t)r0 * D);
    for (int t = threadIdx.x; t < RPB * D / 4; t += 256) {
        int row = t >> 5;  // 32 float4 per row
        float w = inv[r0 + row];
        float4 v = src4[t];
        v.x *= w; v.y *= w; v.z *= w; v.w *= w;
        ((float4*)h)[t] = v;
    }
    __syncthreads();

    int c = threadIdx.x & 127;
    int rh = threadIdx.x >> 7;  // 0 or 1 -> rows rh*8 .. rh*8+7
    float acc[8];
#pragma unroll
    for (int j = 0; j < 8; ++j) acc[j] = 0.0f;

    for (int k = 0; k < D; ++k) {
        float wt = Wt[k * D + c];  // coalesced across lanes
#pragma unroll
        for (int j = 0; j < 8; ++j) acc[j] += h[rh * 8 + j][k] * wt;  // LDS broadcast
    }

    float bc = b[c];
#pragma unroll
    for (int j = 0; j < 8; ++j) {
        io[(size_t)(r0 + rh * 8 + j) * D + c] = acc[j] + bc;
    }
}

extern "C" void kernel_launch(void* const* d_in, const int* in_sizes, int n_in,
                              void* d_out, int out_size, void* d_ws, size_t ws_size,
                              hipStream_t stream) {
    const float* x  = (const float*)d_in[0];
    const int*   ei = (const int*)d_in[1];
    const float* W  = (const float*)d_in[2];
    const float* b  = (const float*)d_in[3];
    float* out = (float*)d_out;

    float* deg = (float*)d_ws;                          // NN floats -> becomes inv_norm
    float* Wt  = (float*)((char*)d_ws + 204800);        // 128*128 floats

    // zero the degree accumulator (ws is NOT re-poisoned between replays)
    hipMemsetAsync(d_ws, 0, NN * sizeof(float), stream);

    deg_kernel<<<2048, 256, 0, stream>>>(ei, deg, NE);
    inv_kernel<<<(NN + 255) / 256, 256, 0, stream>>>(deg, NN);
    transpose_w<<<64, 256, 0, stream>>>(W, Wt);
    init_agg<<<2048, 256, 0, stream>>>(x, deg, out, NN * (D / 4));
    scatter_kernel<<<2048, 256, 0, stream>>>(x, ei, deg, out, NE);
    gemm_kernel<<<NN / RPB, 256, 0, stream>>>(out, deg, Wt, b);
}

// Round 2
// 559.686 us; speedup vs baseline: 2.5951x; 2.5951x over previous
//
#include <hip/hip_runtime.h>

#define NN 50000
#define NE 1600000
#define D 128
#define RPB 16  // rows per block in the GEMM epilogue

// ---- workspace layout (bytes) ----
#define WS_DEG    0            // float NN      (becomes inv_norm)
#define WS_CNT    200704       // int NN        (dst histogram)
#define WS_ZERO_BYTES 400704   // memset deg+cnt in one shot
#define WS_WT     401408       // float 128*128
#define WS_OFF    467200       // int NN+1      (CSR offsets)
#define WS_CUR    667648       // int NN        (fill cursors)
#define WS_CSR    868352       // int NE        (src ids grouped by dst)

// ---------------- histogram: deg[src]++ (float), cnt[dst]++ (int) ----------------
__global__ void hist_kernel(const int* __restrict__ ei, float* __restrict__ deg,
                            int* __restrict__ cnt, int E) {
    int i = blockIdx.x * blockDim.x + threadIdx.x;
    int stride = gridDim.x * blockDim.x;
    for (int e = i; e < E; e += stride) {
        unsafeAtomicAdd(&deg[ei[e]], 1.0f);
        atomicAdd(&cnt[ei[NE + e]], 1);
    }
}

// ---------------- inv_norm[i] = rsqrt(deg[i]+1), in place ----------------
__global__ void inv_kernel(float* __restrict__ deg, int n) {
    int i = blockIdx.x * blockDim.x + threadIdx.x;
    if (i < n) deg[i] = rsqrtf(deg[i] + 1.0f);
}

// ---------------- exclusive scan of cnt -> off, cursor (single 1024-thread block) ----------------
__global__ __launch_bounds__(1024) void scan_kernel(const int* __restrict__ cnt,
                                                    int* __restrict__ off,
                                                    int* __restrict__ cursor) {
    __shared__ int sums[1024];
    int tid = threadIdx.x;
    const int CH = (NN + 1023) / 1024;  // 49
    int lo = tid * CH;
    int hi = lo + CH; if (hi > NN) hi = NN; if (lo > NN) lo = NN;
    int s = 0;
    for (int i = lo; i < hi; ++i) s += cnt[i];
    sums[tid] = s;
    __syncthreads();
    // Hillis-Steele inclusive scan over the 1024 chunk sums
    for (int d = 1; d < 1024; d <<= 1) {
        int v = (tid >= d) ? sums[tid - d] : 0;
        __syncthreads();
        sums[tid] += v;
        __syncthreads();
    }
    int run = (tid == 0) ? 0 : sums[tid - 1];  // exclusive prefix of this chunk
    for (int i = lo; i < hi; ++i) {
        off[i] = run;
        cursor[i] = run;
        run += cnt[i];
    }
    if (tid == 1023) off[NN] = run;  // == NE
}

// ---------------- fill: csr[pos++] = src, grouped by dst ----------------
__global__ void fill_kernel(const int* __restrict__ ei, int* __restrict__ cursor,
                            int* __restrict__ csr, int E) {
    int i = blockIdx.x * blockDim.x + threadIdx.x;
    int stride = gridDim.x * blockDim.x;
    for (int e = i; e < E; e += stride) {
        int d = ei[NE + e];
        int pos = atomicAdd(&cursor[d], 1);
        csr[pos] = ei[e];
    }
}

// ---------------- Wt[k][c] = W[c][k] ----------------
__global__ void transpose_w(const float* __restrict__ W, float* __restrict__ Wt) {
    int i = blockIdx.x * blockDim.x + threadIdx.x;  // 16384 total
    int c = i >> 7;
    int k = i & 127;
    Wt[k * D + c] = W[i];
}

// ---------------- gather: out[n] = inv[n] * (x[n]*inv[n] + sum_{s in in(n)} x[s]*inv[s]) ----------------
// one wave per node, each lane owns 2 columns (float2); no atomics
__global__ __launch_bounds__(256) void gather_kernel(const float* __restrict__ x,
                                                     const float* __restrict__ inv,
                                                     const int* __restrict__ off,
                                                     const int* __restrict__ csr,
                                                     float* __restrict__ out) {
    int wave = (blockIdx.x * blockDim.x + threadIdx.x) >> 6;
    int lane = threadIdx.x & 63;
    if (wave >= NN) return;
    float wn = inv[wave];
    float2 acc = *(const float2*)(x + (size_t)wave * D + lane * 2);
    acc.x *= wn; acc.y *= wn;
    int e = off[wave], e1 = off[wave + 1];
    // unrolled-by-2 to keep two row loads in flight
    for (; e + 1 < e1; e += 2) {
        int s0 = csr[e], s1 = csr[e + 1];
        float w0 = inv[s0], w1 = inv[s1];
        float2 v0 = *(const float2*)(x + (size_t)s0 * D + lane * 2);
        float2 v1 = *(const float2*)(x + (size_t)s1 * D + lane * 2);
        acc.x += v0.x * w0; acc.y += v0.y * w0;
        acc.x += v1.x * w1; acc.y += v1.y * w1;
    }
    if (e < e1) {
        int s = csr[e];
        float w = inv[s];
        float2 v = *(const float2*)(x + (size_t)s * D + lane * 2);
        acc.x += v.x * w; acc.y += v.y * w;
    }
    acc.x *= wn; acc.y *= wn;
    *(float2*)(out + (size_t)wave * D + lane * 2) = acc;
}

// ---------------- out[r][c] = h[r][:] . Wt[:][c] + b[c]  (in-place in io) ----------------
__global__ __launch_bounds__(256) void gemm_kernel(float* io, const float* __restrict__ Wt,
                                                   const float* __restrict__ b) {
    __shared__ float h[RPB][D];
    int r0 = blockIdx.x * RPB;

    const float4* src4 = (const float4*)(io + (size_t)r0 * D);
    for (int t = threadIdx.x; t < RPB * D / 4; t += 256) {
        ((float4*)h)[t] = src4[t];
    }
    __syncthreads();

    int c = threadIdx.x & 127;
    int rh = threadIdx.x >> 7;  // 0 or 1 -> rows rh*8 .. rh*8+7
    float acc[8];
#pragma unroll
    for (int j = 0; j < 8; ++j) acc[j] = 0.0f;

    for (int k = 0; k < D; ++k) {
        float wt = Wt[k * D + c];  // coalesced across lanes
#pragma unroll
        for (int j = 0; j < 8; ++j) acc[j] += h[rh * 8 + j][k] * wt;  // LDS broadcast
    }

    float bc = b[c];
#pragma unroll
    for (int j = 0; j < 8; ++j) {
        io[(size_t)(r0 + rh * 8 + j) * D + c] = acc[j] + bc;
    }
}

extern "C" void kernel_launch(void* const* d_in, const int* in_sizes, int n_in,
                              void* d_out, int out_size, void* d_ws, size_t ws_size,
                              hipStream_t stream) {
    const float* x  = (const float*)d_in[0];
    const int*   ei = (const int*)d_in[1];
    const float* W  = (const float*)d_in[2];
    const float* b  = (const float*)d_in[3];
    float* out = (float*)d_out;

    char* ws = (char*)d_ws;
    float* deg    = (float*)(ws + WS_DEG);   // -> inv after inv_kernel
    int*   cnt    = (int*)  (ws + WS_CNT);
    float* Wt     = (float*)(ws + WS_WT);
    int*   off    = (int*)  (ws + WS_OFF);
    int*   cursor = (int*)  (ws + WS_CUR);
    int*   csr    = (int*)  (ws + WS_CSR);

    // zero deg + cnt (ws is NOT re-poisoned between replays)
    hipMemsetAsync(ws, 0, WS_ZERO_BYTES, stream);

    hist_kernel<<<2048, 256, 0, stream>>>(ei, deg, cnt, NE);
    inv_kernel<<<(NN + 255) / 256, 256, 0, stream>>>(deg, NN);
    scan_kernel<<<1, 1024, 0, stream>>>(cnt, off, cursor);
    fill_kernel<<<2048, 256, 0, stream>>>(ei, cursor, csr, NE);
    transpose_w<<<64, 256, 0, stream>>>(W, Wt);
    gather_kernel<<<(NN * 64 + 255) / 256, 256, 0, stream>>>(x, deg, off, csr, out);
    gemm_kernel<<<NN / RPB, 256, 0, stream>>>(out, Wt, b);
}

// Round 3
// 304.813 us; speedup vs baseline: 4.7649x; 1.8362x over previous
//
#include <hip/hip_runtime.h>

#define NN 50000
#define NE 1600000
#define D 128
#define RPB 16     // rows per block in the GEMM epilogue
#define CAP 80     // fixed CSR capacity per node (Poisson(32) tail @80 ~ 1e-11/node)
#define NR 4       // histogram key ranges
#define NC 64      // edge chunks per range
#define RNG 12500  // NN / NR keys per range
#define CHUNK 25000// NE / NC edges per chunk

// ---- workspace layout (bytes) ----
#define WS_INV 0         // float NN
#define WS_CNT 204800    // int NN (dst fill cursor == dst degree)
#define WS_WT  409600    // float 128*128
#define WS_BIG 475136    // partial hists (12.8 MB) then reused as fixed CSR (16 MB)

// ---------------- src-degree histogram, LDS-privatized by key range ----------------
// grid = NR*NC blocks: r = bid>>6 owns keys [r*RNG,(r+1)*RNG), c = bid&63 owns edges [c*CHUNK, ...)
__global__ __launch_bounds__(1024) void hist_src(const int* __restrict__ ei,
                                                 int* __restrict__ partial) {
    __shared__ int h[RNG];
    int r = blockIdx.x >> 6, c = blockIdx.x & 63;
    int lo = r * RNG;
    for (int j = threadIdx.x; j < RNG; j += 1024) h[j] = 0;
    __syncthreads();
    const int* src = ei + c * CHUNK;
    for (int i = threadIdx.x; i < CHUNK; i += 1024) {
        int k = src[i] - lo;
        if ((unsigned)k < RNG) atomicAdd(&h[k], 1);
    }
    __syncthreads();
    int* p = partial + (size_t)blockIdx.x * RNG;
    for (int j = threadIdx.x; j < RNG; j += 1024) p[j] = h[j];
}

// ---------------- inv[k] = rsqrt(sum_c partial[(r*NC+c)][j] + 1) ----------------
__global__ void reduce_inv(const int* __restrict__ partial, float* __restrict__ inv) {
    int k = blockIdx.x * blockDim.x + threadIdx.x;
    if (k >= NN) return;
    int r = k / RNG, j = k - r * RNG;
    const int* p = partial + (size_t)(r * NC) * RNG + j;
    int s = 0;
#pragma unroll 8
    for (int c = 0; c < NC; ++c) s += p[(size_t)c * RNG];
    inv[k] = rsqrtf((float)s + 1.0f);
}

// ---------------- fill fixed-capacity CSR; cnt doubles as dst degree ----------------
__global__ void fill_fixed(const int* __restrict__ ei, int* __restrict__ cnt,
                           int* __restrict__ csr, int E) {
    int i = blockIdx.x * blockDim.x + threadIdx.x;
    int stride = gridDim.x * blockDim.x;
    for (int e = i; e < E; e += stride) {
        int d = ei[NE + e];
        int pos = atomicAdd(&cnt[d], 1);
        csr[(size_t)d * CAP + pos] = ei[e];
    }
}

// ---------------- Wt[k][c] = W[c][k] ----------------
__global__ void transpose_w(const float* __restrict__ W, float* __restrict__ Wt) {
    int i = blockIdx.x * blockDim.x + threadIdx.x;  // 16384 total
    int c = i >> 7;
    int k = i & 127;
    Wt[k * D + c] = W[i];
}

// ---------------- gather: out[n] = inv[n]*(x[n]*inv[n] + sum_s x[s]*inv[s]) ----------------
// one wave per node; lanes 0-31 take even edges, 32-63 odd edges; each lane owns 4 cols
__global__ __launch_bounds__(256) void gather_kernel(const float* __restrict__ x,
                                                     const float* __restrict__ inv,
                                                     const int* __restrict__ cnt,
                                                     const int* __restrict__ csr,
                                                     float* __restrict__ out) {
    int wid = (blockIdx.x * blockDim.x + threadIdx.x) >> 6;
    if (wid >= NN) return;
    int lane = threadIdx.x & 63;
    int half = lane >> 5;
    int col4 = lane & 31;

    float wn = inv[wid];
    float ax = 0.f, ay = 0.f, az = 0.f, aw = 0.f;
    if (half == 0) {
        float4 v = ((const float4*)(x + (size_t)wid * D))[col4];
        ax = v.x * wn; ay = v.y * wn; az = v.z * wn; aw = v.w * wn;
    }
    int n = cnt[wid];
    const int* row = csr + (size_t)wid * CAP;
    int i = half;
    for (; i + 2 < n; i += 4) {
        int s0 = row[i], s1 = row[i + 2];
        float w0 = inv[s0], w1 = inv[s1];
        float4 v0 = ((const float4*)(x + (size_t)s0 * D))[col4];
        float4 v1 = ((const float4*)(x + (size_t)s1 * D))[col4];
        ax += v0.x * w0 + v1.x * w1;
        ay += v0.y * w0 + v1.y * w1;
        az += v0.z * w0 + v1.z * w1;
        aw += v0.w * w0 + v1.w * w1;
    }
    for (; i < n; i += 2) {
        int s = row[i];
        float w = inv[s];
        float4 v = ((const float4*)(x + (size_t)s * D))[col4];
        ax += v.x * w; ay += v.y * w; az += v.z * w; aw += v.w * w;
    }
    // combine even/odd halves (lane ^ 32)
    ax += __shfl_xor(ax, 32, 64);
    ay += __shfl_xor(ay, 32, 64);
    az += __shfl_xor(az, 32, 64);
    aw += __shfl_xor(aw, 32, 64);
    if (half == 0) {
        float4 o;
        o.x = ax * wn; o.y = ay * wn; o.z = az * wn; o.w = aw * wn;
        ((float4*)(out + (size_t)wid * D))[col4] = o;
    }
}

// ---------------- out[r][c] = h[r][:] . Wt[:][c] + b[c]  (in-place in io) ----------------
__global__ __launch_bounds__(256) void gemm_kernel(float* io, const float* __restrict__ Wt,
                                                   const float* __restrict__ b) {
    __shared__ float h[RPB][D];
    int r0 = blockIdx.x * RPB;

    const float4* src4 = (const float4*)(io + (size_t)r0 * D);
    for (int t = threadIdx.x; t < RPB * D / 4; t += 256) {
        ((float4*)h)[t] = src4[t];
    }
    __syncthreads();

    int c = threadIdx.x & 127;
    int rh = threadIdx.x >> 7;
    float acc[8];
#pragma unroll
    for (int j = 0; j < 8; ++j) acc[j] = 0.0f;

    for (int k = 0; k < D; ++k) {
        float wt = Wt[k * D + c];
#pragma unroll
        for (int j = 0; j < 8; ++j) acc[j] += h[rh * 8 + j][k] * wt;
    }

    float bc = b[c];
#pragma unroll
    for (int j = 0; j < 8; ++j) {
        io[(size_t)(r0 + rh * 8 + j) * D + c] = acc[j] + bc;
    }
}

extern "C" void kernel_launch(void* const* d_in, const int* in_sizes, int n_in,
                              void* d_out, int out_size, void* d_ws, size_t ws_size,
                              hipStream_t stream) {
    const float* x  = (const float*)d_in[0];
    const int*   ei = (const int*)d_in[1];
    const float* W  = (const float*)d_in[2];
    const float* b  = (const float*)d_in[3];
    float* out = (float*)d_out;

    char* ws = (char*)d_ws;
    float* inv = (float*)(ws + WS_INV);
    int*   cnt = (int*)  (ws + WS_CNT);
    float* Wt  = (float*)(ws + WS_WT);
    int*   big = (int*)  (ws + WS_BIG);  // partial hists, then CSR

    // zero the dst cursors (ws is NOT re-poisoned between replays)
    hipMemsetAsync(cnt, 0, NN * sizeof(int), stream);

    hist_src<<<NR * NC, 1024, 0, stream>>>(ei, big);
    reduce_inv<<<(NN + 255) / 256, 256, 0, stream>>>(big, inv);
    transpose_w<<<64, 256, 0, stream>>>(W, Wt);
    fill_fixed<<<2048, 256, 0, stream>>>(ei, cnt, big /* now CSR */, NE);
    gather_kernel<<<(NN * 64 + 255) / 256, 256, 0, stream>>>(x, inv, cnt, big, out);
    gemm_kernel<<<NN / RPB, 256, 0, stream>>>(out, Wt, b);
}

// Round 4
// 297.582 us; speedup vs baseline: 4.8807x; 1.0243x over previous
//
#include <hip/hip_runtime.h>

#define NN 50000
#define NE 1600000
#define D 128
#define RPB 16      // rows per block in the GEMM epilogue
#define NR 8        // key ranges (dst/src value partitions)
#define NC 32       // edge chunks
#define RNG 6250    // NN / NR keys per range
#define CHUNK 50000 // NE / NC edges per chunk

// ---- workspace layout (bytes) ----
#define WS_INV  0         // float NN
#define WS_CNT  204800    // int NN   (dst degree)
#define WS_OFF  409600    // int NN+1 (CSR offsets)
#define WS_WT   614400    // float 128*128
#define WS_PDST 679936    // int NR*NC*RNG = 6.4 MB (counts -> absolute bases)
#define WS_CSR  7079936   // int NE = 6.4 MB; PSRC overlaps here (consumed before fill)

// ---------------- one pass: src hist + dst per-chunk counts (LDS private) ----------------
// grid = NR*NC = 256 blocks; r = bid>>5 owns keys [r*RNG,(r+1)*RNG), c = bid&31 owns chunk c
__global__ __launch_bounds__(1024) void hist_both(const int* __restrict__ ei,
                                                  int* __restrict__ psrc,
                                                  int* __restrict__ pdst) {
    __shared__ int hs[RNG];
    __shared__ int hd[RNG];
    int r = blockIdx.x >> 5, c = blockIdx.x & 31;
    int lo = r * RNG;
    for (int j = threadIdx.x; j < RNG; j += 1024) { hs[j] = 0; hd[j] = 0; }
    __syncthreads();
    const int* s = ei + c * CHUNK;
    const int* d = ei + NE + c * CHUNK;
    for (int i = threadIdx.x; i < CHUNK; i += 1024) {
        int ks = s[i] - lo;
        if ((unsigned)ks < RNG) atomicAdd(&hs[ks], 1);
        int kd = d[i] - lo;
        if ((unsigned)kd < RNG) atomicAdd(&hd[kd], 1);
    }
    __syncthreads();
    int* ps = psrc + (size_t)blockIdx.x * RNG;
    int* pd = pdst + (size_t)blockIdx.x * RNG;
    for (int j = threadIdx.x; j < RNG; j += 1024) { ps[j] = hs[j]; pd[j] = hd[j]; }
}

// ---------------- inv[k] = rsqrt(src_deg+1); cnt[k] = dst_deg ----------------
__global__ void reduce_both(const int* __restrict__ psrc, const int* __restrict__ pdst,
                            float* __restrict__ inv, int* __restrict__ cnt) {
    int k = blockIdx.x * blockDim.x + threadIdx.x;
    if (k >= NN) return;
    int r = k / RNG, j = k - r * RNG;
    size_t base = (size_t)(r * NC) * RNG + j;
    int s = 0, t = 0;
#pragma unroll 8
    for (int c = 0; c < NC; ++c) {
        s += psrc[base + (size_t)c * RNG];
        t += pdst[base + (size_t)c * RNG];
    }
    inv[k] = rsqrtf((float)s + 1.0f);
    cnt[k] = t;
}

// ---------------- exclusive scan of cnt -> off (single block) ----------------
__global__ __launch_bounds__(1024) void scan_nodes(const int* __restrict__ cnt,
                                                   int* __restrict__ off) {
    __shared__ int sums[1024];
    int tid = threadIdx.x;
    const int CH = (NN + 1023) / 1024;  // 49
    int lo = tid * CH;
    int hi = lo + CH; if (hi > NN) hi = NN; if (lo > NN) lo = NN;
    int s = 0;
    for (int i = lo; i < hi; ++i) s += cnt[i];
    sums[tid] = s;
    __syncthreads();
    for (int dd = 1; dd < 1024; dd <<= 1) {
        int v = (tid >= dd) ? sums[tid - dd] : 0;
        __syncthreads();
        sums[tid] += v;
        __syncthreads();
    }
    int run = (tid == 0) ? 0 : sums[tid - 1];
    for (int i = lo; i < hi; ++i) { off[i] = run; run += cnt[i]; }
    if (tid == 1023) off[NN] = run;  // == NE
}

// ---------------- pdst counts -> absolute CSR bases (in place) ----------------
__global__ void scan_chunks(int* __restrict__ pdst, const int* __restrict__ off) {
    int k = blockIdx.x * blockDim.x + threadIdx.x;
    if (k >= NN) return;
    int r = k / RNG, j = k - r * RNG;
    size_t base = (size_t)(r * NC) * RNG + j;
    int run = off[k];
#pragma unroll 8
    for (int c = 0; c < NC; ++c) {
        size_t p = base + (size_t)c * RNG;
        int v = pdst[p];
        pdst[p] = run;
        run += v;
    }
}

// ---------------- place edges: LDS cursor atomics only, plain CSR stores ----------------
__global__ __launch_bounds__(1024) void fill_sorted(const int* __restrict__ ei,
                                                    const int* __restrict__ bases,
                                                    int* __restrict__ csr) {
    __shared__ int cur[RNG];
    int r = blockIdx.x >> 5, c = blockIdx.x & 31;
    int lo = r * RNG;
    const int* bslice = bases + (size_t)blockIdx.x * RNG;
    for (int j = threadIdx.x; j < RNG; j += 1024) cur[j] = bslice[j];
    __syncthreads();
    const int* s = ei + c * CHUNK;
    const int* d = ei + NE + c * CHUNK;
    for (int i = threadIdx.x; i < CHUNK; i += 1024) {
        int kd = d[i] - lo;
        if ((unsigned)kd < RNG) {
            int pos = atomicAdd(&cur[kd], 1);
            csr[pos] = s[i];
        }
    }
}

// ---------------- Wt[k][c] = W[c][k] ----------------
__global__ void transpose_w(const float* __restrict__ W, float* __restrict__ Wt) {
    int i = blockIdx.x * blockDim.x + threadIdx.x;  // 16384 total
    int c = i >> 7;
    int k = i & 127;
    Wt[k * D + c] = W[i];
}

// ---------------- gather: out[n] = inv[n]*(x[n]*inv[n] + sum_s x[s]*inv[s]) ----------------
// one wave per node; lanes 0-31 even edges, 32-63 odd edges; each lane owns 4 cols; 4 rows in flight per half
__global__ __launch_bounds__(256) void gather_kernel(const float* __restrict__ x,
                                                     const float* __restrict__ inv,
                                                     const int* __restrict__ off,
                                                     const int* __restrict__ cnt,
                                                     const int* __restrict__ csr,
                                                     float* __restrict__ out) {
    int wid = (blockIdx.x * blockDim.x + threadIdx.x) >> 6;
    if (wid >= NN) return;
    int lane = threadIdx.x & 63;
    int half = lane >> 5;
    int col4 = lane & 31;

    float wn = inv[wid];
    float ax = 0.f, ay = 0.f, az = 0.f, aw = 0.f;
    if (half == 0) {
        float4 v = ((const float4*)(x + (size_t)wid * D))[col4];
        ax = v.x * wn; ay = v.y * wn; az = v.z * wn; aw = v.w * wn;
    }
    int n = cnt[wid];
    const int* row = csr + off[wid];
    int i = half;
    for (; i + 6 < n; i += 8) {
        int s0 = row[i], s1 = row[i + 2], s2 = row[i + 4], s3 = row[i + 6];
        float w0 = inv[s0], w1 = inv[s1], w2 = inv[s2], w3 = inv[s3];
        float4 v0 = ((const float4*)(x + (size_t)s0 * D))[col4];
        float4 v1 = ((const float4*)(x + (size_t)s1 * D))[col4];
        float4 v2 = ((const float4*)(x + (size_t)s2 * D))[col4];
        float4 v3 = ((const float4*)(x + (size_t)s3 * D))[col4];
        ax += v0.x * w0 + v1.x * w1 + v2.x * w2 + v3.x * w3;
        ay += v0.y * w0 + v1.y * w1 + v2.y * w2 + v3.y * w3;
        az += v0.z * w0 + v1.z * w1 + v2.z * w2 + v3.z * w3;
        aw += v0.w * w0 + v1.w * w1 + v2.w * w2 + v3.w * w3;
    }
    for (; i < n; i += 2) {
        int s = row[i];
        float w = inv[s];
        float4 v = ((const float4*)(x + (size_t)s * D))[col4];
        ax += v.x * w; ay += v.y * w; az += v.z * w; aw += v.w * w;
    }
    ax += __shfl_xor(ax, 32, 64);
    ay += __shfl_xor(ay, 32, 64);
    az += __shfl_xor(az, 32, 64);
    aw += __shfl_xor(aw, 32, 64);
    if (half == 0) {
        float4 o;
        o.x = ax * wn; o.y = ay * wn; o.z = az * wn; o.w = aw * wn;
        ((float4*)(out + (size_t)wid * D))[col4] = o;
    }
}

// ---------------- out[r][c] = h[r][:] . Wt[:][c] + b[c]  (in-place in io) ----------------
__global__ __launch_bounds__(256) void gemm_kernel(float* io, const float* __restrict__ Wt,
                                                   const float* __restrict__ b) {
    __shared__ float h[RPB][D];
    int r0 = blockIdx.x * RPB;

    const float4* src4 = (const float4*)(io + (size_t)r0 * D);
    for (int t = threadIdx.x; t < RPB * D / 4; t += 256) {
        ((float4*)h)[t] = src4[t];
    }
    __syncthreads();

    int c = threadIdx.x & 127;
    int rh = threadIdx.x >> 7;
    float acc[8];
#pragma unroll
    for (int j = 0; j < 8; ++j) acc[j] = 0.0f;

    for (int k = 0; k < D; ++k) {
        float wt = Wt[k * D + c];
#pragma unroll
        for (int j = 0; j < 8; ++j) acc[j] += h[rh * 8 + j][k] * wt;
    }

    float bc = b[c];
#pragma unroll
    for (int j = 0; j < 8; ++j) {
        io[(size_t)(r0 + rh * 8 + j) * D + c] = acc[j] + bc;
    }
}

extern "C" void kernel_launch(void* const* d_in, const int* in_sizes, int n_in,
                              void* d_out, int out_size, void* d_ws, size_t ws_size,
                              hipStream_t stream) {
    const float* x  = (const float*)d_in[0];
    const int*   ei = (const int*)d_in[1];
    const float* W  = (const float*)d_in[2];
    const float* b  = (const float*)d_in[3];
    float* out = (float*)d_out;

    char* ws = (char*)d_ws;
    float* inv  = (float*)(ws + WS_INV);
    int*   cnt  = (int*)  (ws + WS_CNT);
    int*   off  = (int*)  (ws + WS_OFF);
    float* Wt   = (float*)(ws + WS_WT);
    int*   pdst = (int*)  (ws + WS_PDST);
    int*   csr  = (int*)  (ws + WS_CSR);
    int*   psrc = csr;  // overlaps CSR: consumed by reduce_both before fill writes CSR

    hist_both<<<NR * NC, 1024, 0, stream>>>(ei, psrc, pdst);
    reduce_both<<<(NN + 255) / 256, 256, 0, stream>>>(psrc, pdst, inv, cnt);
    scan_nodes<<<1, 1024, 0, stream>>>(cnt, off);
    scan_chunks<<<(NN + 255) / 256, 256, 0, stream>>>(pdst, off);
    transpose_w<<<64, 256, 0, stream>>>(W, Wt);
    fill_sorted<<<NR * NC, 1024, 0, stream>>>(ei, pdst, csr);
    gather_kernel<<<(NN * 64 + 255) / 256, 256, 0, stream>>>(x, inv, off, cnt, csr, out);
    gemm_kernel<<<NN / RPB, 256, 0, stream>>>(out, Wt, b);
}

// Round 5
// 268.930 us; speedup vs baseline: 5.4007x; 1.1065x over previous
//
#include <hip/hip_runtime.h>

#define NN 50000
#define NE 1600000
#define D 128
#define RPB 16      // rows per block in the GEMM epilogue
#define NR 2        // key ranges (node-id partitions)
#define NC 32       // edge chunks
#define RNG 25000   // NN / NR keys per range
#define CHUNK 50000 // NE / NC edges per chunk

// ---- workspace layout (bytes) ----
#define WS_INV  0         // float NN
#define WS_CNT  204800    // int NN   (dst degree)
#define WS_OFF  409600    // int NN+1 (CSR offsets)
#define WS_WT   614400    // float 128*128
#define WS_PDST 679936    // int NR*NC*RNG = 6.4 MB (dst counts -> absolute bases)
#define WS_PSRC 7079936   // int NR*NC*RNG = 6.4 MB (src counts)
#define WS_CSR  13479936  // int NE = 6.4 MB
#define WS_XNB  679936    // ushort NN*128 = 12.8 MB, OVERWRITES pdst+psrc after fill
// total footprint: 19,879,936 bytes

// ---------------- src histogram, LDS-privatized (reads only ei[0:NE]) ----------------
__global__ __launch_bounds__(1024) void hist_src(const int* __restrict__ ei,
                                                 int* __restrict__ psrc) {
    __shared__ int h[RNG];
    int r = blockIdx.x >> 5, c = blockIdx.x & 31;
    int lo = r * RNG;
    for (int j = threadIdx.x; j < RNG; j += 1024) h[j] = 0;
    __syncthreads();
    const int* s = ei + c * CHUNK;
    for (int i = threadIdx.x; i < CHUNK; i += 1024) {
        int k = s[i] - lo;
        if ((unsigned)k < RNG) atomicAdd(&h[k], 1);
    }
    __syncthreads();
    int* p = psrc + (size_t)blockIdx.x * RNG;
    for (int j = threadIdx.x; j < RNG; j += 1024) p[j] = h[j];
}

// ---------------- dst per-chunk counts (reads only ei[NE:2NE]) ----------------
__global__ __launch_bounds__(1024) void hist_dst(const int* __restrict__ ei,
                                                 int* __restrict__ pdst) {
    __shared__ int h[RNG];
    int r = blockIdx.x >> 5, c = blockIdx.x & 31;
    int lo = r * RNG;
    for (int j = threadIdx.x; j < RNG; j += 1024) h[j] = 0;
    __syncthreads();
    const int* d = ei + NE + c * CHUNK;
    for (int i = threadIdx.x; i < CHUNK; i += 1024) {
        int k = d[i] - lo;
        if ((unsigned)k < RNG) atomicAdd(&h[k], 1);
    }
    __syncthreads();
    int* p = pdst + (size_t)blockIdx.x * RNG;
    for (int j = threadIdx.x; j < RNG; j += 1024) p[j] = h[j];
}

// ---------------- inv[k] = rsqrt(src_deg+1); cnt[k] = dst_deg ----------------
__global__ void reduce_both(const int* __restrict__ psrc, const int* __restrict__ pdst,
                            float* __restrict__ inv, int* __restrict__ cnt) {
    int k = blockIdx.x * blockDim.x + threadIdx.x;
    if (k >= NN) return;
    int r = k / RNG, j = k - r * RNG;
    size_t base = (size_t)(r * NC) * RNG + j;
    int s = 0, t = 0;
#pragma unroll 8
    for (int c = 0; c < NC; ++c) {
        s += psrc[base + (size_t)c * RNG];
        t += pdst[base + (size_t)c * RNG];
    }
    inv[k] = rsqrtf((float)s + 1.0f);
    cnt[k] = t;
}

// ---------------- exclusive scan of cnt -> off (single block) ----------------
__global__ __launch_bounds__(1024) void scan_nodes(const int* __restrict__ cnt,
                                                   int* __restrict__ off) {
    __shared__ int sums[1024];
    int tid = threadIdx.x;
    const int CH = (NN + 1023) / 1024;  // 49
    int lo = tid * CH;
    int hi = lo + CH; if (hi > NN) hi = NN; if (lo > NN) lo = NN;
    int s = 0;
    for (int i = lo; i < hi; ++i) s += cnt[i];
    sums[tid] = s;
    __syncthreads();
    for (int dd = 1; dd < 1024; dd <<= 1) {
        int v = (tid >= dd) ? sums[tid - dd] : 0;
        __syncthreads();
        sums[tid] += v;
        __syncthreads();
    }
    int run = (tid == 0) ? 0 : sums[tid - 1];
    for (int i = lo; i < hi; ++i) { off[i] = run; run += cnt[i]; }
    if (tid == 1023) off[NN] = run;  // == NE
}

// ---------------- pdst counts -> absolute CSR bases (in place) ----------------
__global__ void scan_chunks(int* __restrict__ pdst, const int* __restrict__ off) {
    int k = blockIdx.x * blockDim.x + threadIdx.x;
    if (k >= NN) return;
    int r = k / RNG, j = k - r * RNG;
    size_t base = (size_t)(r * NC) * RNG + j;
    int run = off[k];
#pragma unroll 8
    for (int c = 0; c < NC; ++c) {
        size_t p = base + (size_t)c * RNG;
        int v = pdst[p];
        pdst[p] = run;
        run += v;
    }
}

// ---------------- place edges: LDS cursor atomics only, plain CSR stores ----------------
__global__ __launch_bounds__(1024) void fill_sorted(const int* __restrict__ ei,
                                                    const int* __restrict__ bases,
                                                    int* __restrict__ csr) {
    __shared__ int cur[RNG];
    int r = blockIdx.x >> 5, c = blockIdx.x & 31;
    int lo = r * RNG;
    const int* bslice = bases + (size_t)blockIdx.x * RNG;
    for (int j = threadIdx.x; j < RNG; j += 1024) cur[j] = bslice[j];
    __syncthreads();
    const int* s = ei + c * CHUNK;
    const int* d = ei + NE + c * CHUNK;
    for (int i = threadIdx.x; i < CHUNK; i += 1024) {
        int kd = d[i] - lo;
        if ((unsigned)kd < RNG) {
            int pos = atomicAdd(&cur[kd], 1);
            csr[pos] = s[i];
        }
    }
}

// ---------------- Wt[k][c] = W[c][k] ----------------
__global__ void transpose_w(const float* __restrict__ W, float* __restrict__ Wt) {
    int i = blockIdx.x * blockDim.x + threadIdx.x;  // 16384 total
    int c = i >> 7;
    int k = i & 127;
    Wt[k * D + c] = W[i];
}

// ---------------- xnb[n][c] = bf16_rne(x[n][c] * inv[n]), packed 2/u32 ----------------
__device__ __forceinline__ unsigned bf16_rne(float f) {
    unsigned u = __float_as_uint(f);
    return (u + 0x7fffu + ((u >> 16) & 1u)) >> 16;
}
__global__ void scale_kernel(const float* __restrict__ x, const float* __restrict__ inv,
                             unsigned* __restrict__ xnb4) {
    // each thread: 8 floats -> 4 packed u32 (uint4 store); 16 threads per row
    int i = blockIdx.x * blockDim.x + threadIdx.x;  // 0 .. NN*16-1
    if (i >= NN * 16) return;
    int row = i >> 4;
    float w = inv[row];
    const float4* src = (const float4*)(x + (size_t)i * 8);
    float4 a = src[0], bq = src[1];
    uint4 o;
    o.x = bf16_rne(a.x * w)  | (bf16_rne(a.y * w) << 16);
    o.y = bf16_rne(a.z * w)  | (bf16_rne(a.w * w) << 16);
    o.z = bf16_rne(bq.x * w) | (bf16_rne(bq.y * w) << 16);
    o.w = bf16_rne(bq.z * w) | (bf16_rne(bq.w * w) << 16);
    ((uint4*)xnb4)[i] = o;
}

// ---------------- gather: out[n] = inv[n]*(xnb[n] + sum_s xnb[s]) ----------------
// one wave per node; lanes 0-31 even edges, 32-63 odd; each lane owns 4 cols (8B bf16)
__global__ __launch_bounds__(256) void gather_kernel(const unsigned* __restrict__ xnb,
                                                     const float* __restrict__ inv,
                                                     const int* __restrict__ off,
                                                     const int* __restrict__ cnt,
                                                     const int* __restrict__ csr,
                                                     float* __restrict__ out) {
    int wid = (blockIdx.x * blockDim.x + threadIdx.x) >> 6;
    if (wid >= NN) return;
    int lane = threadIdx.x & 63;
    int half = lane >> 5;
    int col4 = lane & 31;  // owns cols 4*col4 .. 4*col4+3 (one uint2)

    float ax = 0.f, ay = 0.f, az = 0.f, aw = 0.f;
    const uint2* xb = (const uint2*)xnb;  // 32 uint2 per row
    if (half == 0) {
        uint2 u = xb[(size_t)wid * 32 + col4];
        ax = __uint_as_float(u.x << 16);
        ay = __uint_as_float(u.x & 0xffff0000u);
        az = __uint_as_float(u.y << 16);
        aw = __uint_as_float(u.y & 0xffff0000u);
    }
    int n = cnt[wid];
    const int* row = csr + off[wid];
    int i = half;
    for (; i + 6 < n; i += 8) {
        int s0 = row[i], s1 = row[i + 2], s2 = row[i + 4], s3 = row[i + 6];
        uint2 u0 = xb[(size_t)s0 * 32 + col4];
        uint2 u1 = xb[(size_t)s1 * 32 + col4];
        uint2 u2 = xb[(size_t)s2 * 32 + col4];
        uint2 u3 = xb[(size_t)s3 * 32 + col4];
        ax += __uint_as_float(u0.x << 16) + __uint_as_float(u1.x << 16)
            + __uint_as_float(u2.x << 16) + __uint_as_float(u3.x << 16);
        ay += __uint_as_float(u0.x & 0xffff0000u) + __uint_as_float(u1.x & 0xffff0000u)
            + __uint_as_float(u2.x & 0xffff0000u) + __uint_as_float(u3.x & 0xffff0000u);
        az += __uint_as_float(u0.y << 16) + __uint_as_float(u1.y << 16)
            + __uint_as_float(u2.y << 16) + __uint_as_float(u3.y << 16);
        aw += __uint_as_float(u0.y & 0xffff0000u) + __uint_as_float(u1.y & 0xffff0000u)
            + __uint_as_float(u2.y & 0xffff0000u) + __uint_as_float(u3.y & 0xffff0000u);
    }
    for (; i < n; i += 2) {
        int s = row[i];
        uint2 u = xb[(size_t)s * 32 + col4];
        ax += __uint_as_float(u.x << 16);
        ay += __uint_as_float(u.x & 0xffff0000u);
        az += __uint_as_float(u.y << 16);
        aw += __uint_as_float(u.y & 0xffff0000u);
    }
    ax += __shfl_xor(ax, 32, 64);
    ay += __shfl_xor(ay, 32, 64);
    az += __shfl_xor(az, 32, 64);
    aw += __shfl_xor(aw, 32, 64);
    if (half == 0) {
        float wn = inv[wid];
        float4 o;
        o.x = ax * wn; o.y = ay * wn; o.z = az * wn; o.w = aw * wn;
        ((float4*)(out + (size_t)wid * D))[col4] = o;
    }
}

// ---------------- out[r][c] = h[r][:] . Wt[:][c] + b[c]  (in-place in io) ----------------
__global__ __launch_bounds__(256) void gemm_kernel(float* io, const float* __restrict__ Wt,
                                                   const float* __restrict__ b) {
    __shared__ float h[RPB][D];
    int r0 = blockIdx.x * RPB;

    const float4* src4 = (const float4*)(io + (size_t)r0 * D);
    for (int t = threadIdx.x; t < RPB * D / 4; t += 256) {
        ((float4*)h)[t] = src4[t];
    }
    __syncthreads();

    int c = threadIdx.x & 127;
    int rh = threadIdx.x >> 7;
    float acc[8];
#pragma unroll
    for (int j = 0; j < 8; ++j) acc[j] = 0.0f;

    for (int k = 0; k < D; ++k) {
        float wt = Wt[k * D + c];
#pragma unroll
        for (int j = 0; j < 8; ++j) acc[j] += h[rh * 8 + j][k] * wt;
    }

    float bc = b[c];
#pragma unroll
    for (int j = 0; j < 8; ++j) {
        io[(size_t)(r0 + rh * 8 + j) * D + c] = acc[j] + bc;
    }
}

extern "C" void kernel_launch(void* const* d_in, const int* in_sizes, int n_in,
                              void* d_out, int out_size, void* d_ws, size_t ws_size,
                              hipStream_t stream) {
    const float* x  = (const float*)d_in[0];
    const int*   ei = (const int*)d_in[1];
    const float* W  = (const float*)d_in[2];
    const float* b  = (const float*)d_in[3];
    float* out = (float*)d_out;

    char* ws = (char*)d_ws;
    float*    inv  = (float*)   (ws + WS_INV);
    int*      cnt  = (int*)     (ws + WS_CNT);
    int*      off  = (int*)     (ws + WS_OFF);
    float*    Wt   = (float*)   (ws + WS_WT);
    int*      pdst = (int*)     (ws + WS_PDST);
    int*      psrc = (int*)     (ws + WS_PSRC);
    int*      csr  = (int*)     (ws + WS_CSR);
    unsigned* xnb  = (unsigned*)(ws + WS_XNB);  // overwrites pdst+psrc AFTER fill_sorted

    hist_src<<<NR * NC, 1024, 0, stream>>>(ei, psrc);
    hist_dst<<<NR * NC, 1024, 0, stream>>>(ei, pdst);
    reduce_both<<<(NN + 255) / 256, 256, 0, stream>>>(psrc, pdst, inv, cnt);
    scan_nodes<<<1, 1024, 0, stream>>>(cnt, off);
    scan_chunks<<<(NN + 255) / 256, 256, 0, stream>>>(pdst, off);
    transpose_w<<<64, 256, 0, stream>>>(W, Wt);
    fill_sorted<<<NR * NC, 1024, 0, stream>>>(ei, pdst, csr);
    scale_kernel<<<(NN * 16 + 255) / 256, 256, 0, stream>>>(x, inv, xnb);
    gather_kernel<<<(NN * 64 + 255) / 256, 256, 0, stream>>>(xnb, inv, off, cnt, csr, out);
    gemm_kernel<<<NN / RPB, 256, 0, stream>>>(out, Wt, b);
}

// Round 6
// 197.770 us; speedup vs baseline: 7.3439x; 1.3598x over previous
//
#include <hip/hip_runtime.h>

#define NN 50000
#define NE 1600000
#define D 128
#define RPB 16      // rows per block in the GEMM epilogue
#define NR 2        // key ranges (node-id partitions)
#define NC 32       // edge chunks
#define RNG 25000   // NN / NR keys per range
#define CHUNK 50000 // NE / NC edges per chunk
#define NB 49       // scan blocks = ceil(NN/1024)

// ---- workspace layout (bytes) ----
#define WS_INV  0         // float NN
#define WS_CNT  204800    // int NN   (dst degree)
#define WS_OFF  409600    // int NN   (CSR offsets: local then final)
#define WS_BSUM 610304    // int NB   (per-scan-block sums)
#define WS_WT   614400    // float 128*128
#define WS_PDST 679936    // int NR*NC*RNG = 6.4 MB (dst counts -> absolute bases)
#define WS_PSRC 7079936   // int NR*NC*RNG = 6.4 MB (src counts)
#define WS_CSR  13479936  // int NE = 6.4 MB
#define WS_XNB  679936    // ushort NN*128 = 12.8 MB, OVERWRITES pdst+psrc after fill

// ---------------- src histogram, LDS-privatized (reads only ei[0:NE]) ----------------
__global__ __launch_bounds__(1024) void hist_src(const int* __restrict__ ei,
                                                 int* __restrict__ psrc) {
    __shared__ int h[RNG];
    int r = blockIdx.x >> 5, c = blockIdx.x & 31;
    int lo = r * RNG;
    for (int j = threadIdx.x; j < RNG; j += 1024) h[j] = 0;
    __syncthreads();
    const int* s = ei + c * CHUNK;
    for (int i = threadIdx.x; i < CHUNK; i += 1024) {
        int k = s[i] - lo;
        if ((unsigned)k < RNG) atomicAdd(&h[k], 1);
    }
    __syncthreads();
    int* p = psrc + (size_t)blockIdx.x * RNG;
    for (int j = threadIdx.x; j < RNG; j += 1024) p[j] = h[j];
}

// ---------------- dst per-chunk counts (reads only ei[NE:2NE]) ----------------
__global__ __launch_bounds__(1024) void hist_dst(const int* __restrict__ ei,
                                                 int* __restrict__ pdst) {
    __shared__ int h[RNG];
    int r = blockIdx.x >> 5, c = blockIdx.x & 31;
    int lo = r * RNG;
    for (int j = threadIdx.x; j < RNG; j += 1024) h[j] = 0;
    __syncthreads();
    const int* d = ei + NE + c * CHUNK;
    for (int i = threadIdx.x; i < CHUNK; i += 1024) {
        int k = d[i] - lo;
        if ((unsigned)k < RNG) atomicAdd(&h[k], 1);
    }
    __syncthreads();
    int* p = pdst + (size_t)blockIdx.x * RNG;
    for (int j = threadIdx.x; j < RNG; j += 1024) p[j] = h[j];
}

// ---------------- inv[k] = rsqrt(src_deg+1); cnt[k] = dst_deg ----------------
__global__ void reduce_both(const int* __restrict__ psrc, const int* __restrict__ pdst,
                            float* __restrict__ inv, int* __restrict__ cnt) {
    int k = blockIdx.x * blockDim.x + threadIdx.x;
    if (k >= NN) return;
    int r = k / RNG, j = k - r * RNG;
    size_t base = (size_t)(r * NC) * RNG + j;
    int s = 0, t = 0;
#pragma unroll 8
    for (int c = 0; c < NC; ++c) {
        s += psrc[base + (size_t)c * RNG];
        t += pdst[base + (size_t)c * RNG];
    }
    inv[k] = rsqrtf((float)s + 1.0f);
    cnt[k] = t;
}

// ---------------- phase 1: per-1024-block exclusive scan of cnt ----------------
__global__ __launch_bounds__(1024) void scan_blocks(const int* __restrict__ cnt,
                                                    int* __restrict__ off,
                                                    int* __restrict__ bsum) {
    __shared__ int s[1024];
    int tid = threadIdx.x;
    int i = blockIdx.x * 1024 + tid;
    int v = (i < NN) ? cnt[i] : 0;
    s[tid] = v;
    __syncthreads();
    for (int d = 1; d < 1024; d <<= 1) {
        int t = (tid >= d) ? s[tid - d] : 0;
        __syncthreads();
        s[tid] += t;
        __syncthreads();
    }
    if (i < NN) off[i] = s[tid] - v;  // exclusive within block
    if (tid == 1023) bsum[blockIdx.x] = s[1023];
}

// ---------------- phase 2+3: add block base; pdst counts -> absolute CSR bases ----------------
__global__ void scan_chunks(int* __restrict__ pdst, int* __restrict__ off,
                            const int* __restrict__ bsum) {
    int k = blockIdx.x * blockDim.x + threadIdx.x;
    if (k >= NN) return;
    int bi = k >> 10;
    int top = 0;
#pragma unroll 8
    for (int c = 0; c < bi; ++c) top += bsum[c];  // <=48 L2-broadcast loads
    int run = off[k] + top;
    off[k] = run;  // final CSR offset (same thread read->write, no race)
    int r = k / RNG, j = k - r * RNG;
    size_t base = (size_t)(r * NC) * RNG + j;
#pragma unroll 8
    for (int c = 0; c < NC; ++c) {
        size_t p = base + (size_t)c * RNG;
        int v = pdst[p];
        pdst[p] = run;
        run += v;
    }
}

// ---------------- place edges: LDS cursor atomics only, plain CSR stores ----------------
__global__ __launch_bounds__(1024) void fill_sorted(const int* __restrict__ ei,
                                                    const int* __restrict__ bases,
                                                    int* __restrict__ csr) {
    __shared__ int cur[RNG];
    int r = blockIdx.x >> 5, c = blockIdx.x & 31;
    int lo = r * RNG;
    const int* bslice = bases + (size_t)blockIdx.x * RNG;
    for (int j = threadIdx.x; j < RNG; j += 1024) cur[j] = bslice[j];
    __syncthreads();
    const int* s = ei + c * CHUNK;
    const int* d = ei + NE + c * CHUNK;
    for (int i = threadIdx.x; i < CHUNK; i += 1024) {
        int kd = d[i] - lo;
        if ((unsigned)kd < RNG) {
            int pos = atomicAdd(&cur[kd], 1);
            csr[pos] = s[i];
        }
    }
}

// ---------------- Wt[k][c] = W[c][k] ----------------
__global__ void transpose_w(const float* __restrict__ W, float* __restrict__ Wt) {
    int i = blockIdx.x * blockDim.x + threadIdx.x;  // 16384 total
    int c = i >> 7;
    int k = i & 127;
    Wt[k * D + c] = W[i];
}

// ---------------- xnb[n][c] = bf16_rne(x[n][c] * inv[n]), packed 2/u32 ----------------
__device__ __forceinline__ unsigned bf16_rne(float f) {
    unsigned u = __float_as_uint(f);
    return (u + 0x7fffu + ((u >> 16) & 1u)) >> 16;
}
__global__ void scale_kernel(const float* __restrict__ x, const float* __restrict__ inv,
                             unsigned* __restrict__ xnb4) {
    int i = blockIdx.x * blockDim.x + threadIdx.x;  // 0 .. NN*16-1
    if (i >= NN * 16) return;
    int row = i >> 4;
    float w = inv[row];
    const float4* src = (const float4*)(x + (size_t)i * 8);
    float4 a = src[0], bq = src[1];
    uint4 o;
    o.x = bf16_rne(a.x * w)  | (bf16_rne(a.y * w) << 16);
    o.y = bf16_rne(a.z * w)  | (bf16_rne(a.w * w) << 16);
    o.z = bf16_rne(bq.x * w) | (bf16_rne(bq.y * w) << 16);
    o.w = bf16_rne(bq.z * w) | (bf16_rne(bq.w * w) << 16);
    ((uint4*)xnb4)[i] = o;
}

// ---------------- gather: out[n] = inv[n]*(xnb[n] + sum_s xnb[s]) ----------------
__global__ __launch_bounds__(256) void gather_kernel(const unsigned* __restrict__ xnb,
                                                     const float* __restrict__ inv,
                                                     const int* __restrict__ off,
                                                     const int* __restrict__ cnt,
                                                     const int* __restrict__ csr,
                                                     float* __restrict__ out) {
    int wid = (blockIdx.x * blockDim.x + threadIdx.x) >> 6;
    if (wid >= NN) return;
    int lane = threadIdx.x & 63;
    int half = lane >> 5;
    int col4 = lane & 31;  // owns cols 4*col4 .. 4*col4+3 (one uint2)

    float ax = 0.f, ay = 0.f, az = 0.f, aw = 0.f;
    const uint2* xb = (const uint2*)xnb;  // 32 uint2 per row
    if (half == 0) {
        uint2 u = xb[(size_t)wid * 32 + col4];
        ax = __uint_as_float(u.x << 16);
        ay = __uint_as_float(u.x & 0xffff0000u);
        az = __uint_as_float(u.y << 16);
        aw = __uint_as_float(u.y & 0xffff0000u);
    }
    int n = cnt[wid];
    const int* row = csr + off[wid];
    int i = half;
    for (; i + 6 < n; i += 8) {
        int s0 = row[i], s1 = row[i + 2], s2 = row[i + 4], s3 = row[i + 6];
        uint2 u0 = xb[(size_t)s0 * 32 + col4];
        uint2 u1 = xb[(size_t)s1 * 32 + col4];
        uint2 u2 = xb[(size_t)s2 * 32 + col4];
        uint2 u3 = xb[(size_t)s3 * 32 + col4];
        ax += __uint_as_float(u0.x << 16) + __uint_as_float(u1.x << 16)
            + __uint_as_float(u2.x << 16) + __uint_as_float(u3.x << 16);
        ay += __uint_as_float(u0.x & 0xffff0000u) + __uint_as_float(u1.x & 0xffff0000u)
            + __uint_as_float(u2.x & 0xffff0000u) + __uint_as_float(u3.x & 0xffff0000u);
        az += __uint_as_float(u0.y << 16) + __uint_as_float(u1.y << 16)
            + __uint_as_float(u2.y << 16) + __uint_as_float(u3.y << 16);
        aw += __uint_as_float(u0.y & 0xffff0000u) + __uint_as_float(u1.y & 0xffff0000u)
            + __uint_as_float(u2.y & 0xffff0000u) + __uint_as_float(u3.y & 0xffff0000u);
    }
    for (; i < n; i += 2) {
        int s = row[i];
        uint2 u = xb[(size_t)s * 32 + col4];
        ax += __uint_as_float(u.x << 16);
        ay += __uint_as_float(u.x & 0xffff0000u);
        az += __uint_as_float(u.y << 16);
        aw += __uint_as_float(u.y & 0xffff0000u);
    }
    ax += __shfl_xor(ax, 32, 64);
    ay += __shfl_xor(ay, 32, 64);
    az += __shfl_xor(az, 32, 64);
    aw += __shfl_xor(aw, 32, 64);
    if (half == 0) {
        float wn = inv[wid];
        float4 o;
        o.x = ax * wn; o.y = ay * wn; o.z = az * wn; o.w = aw * wn;
        ((float4*)(out + (size_t)wid * D))[col4] = o;
    }
}

// ---------------- out[r][c] = h[r][:] . Wt[:][c] + b[c]  (in-place in io) ----------------
__global__ __launch_bounds__(256) void gemm_kernel(float* io, const float* __restrict__ Wt,
                                                   const float* __restrict__ b) {
    __shared__ float h[RPB][D];
    int r0 = blockIdx.x * RPB;

    const float4* src4 = (const float4*)(io + (size_t)r0 * D);
    for (int t = threadIdx.x; t < RPB * D / 4; t += 256) {
        ((float4*)h)[t] = src4[t];
    }
    __syncthreads();

    int c = threadIdx.x & 127;
    int rh = threadIdx.x >> 7;
    float acc[8];
#pragma unroll
    for (int j = 0; j < 8; ++j) acc[j] = 0.0f;

    for (int k = 0; k < D; ++k) {
        float wt = Wt[k * D + c];
#pragma unroll
        for (int j = 0; j < 8; ++j) acc[j] += h[rh * 8 + j][k] * wt;
    }

    float bc = b[c];
#pragma unroll
    for (int j = 0; j < 8; ++j) {
        io[(size_t)(r0 + rh * 8 + j) * D + c] = acc[j] + bc;
    }
}

extern "C" void kernel_launch(void* const* d_in, const int* in_sizes, int n_in,
                              void* d_out, int out_size, void* d_ws, size_t ws_size,
                              hipStream_t stream) {
    const float* x  = (const float*)d_in[0];
    const int*   ei = (const int*)d_in[1];
    const float* W  = (const float*)d_in[2];
    const float* b  = (const float*)d_in[3];
    float* out = (float*)d_out;

    char* ws = (char*)d_ws;
    float*    inv  = (float*)   (ws + WS_INV);
    int*      cnt  = (int*)     (ws + WS_CNT);
    int*      off  = (int*)     (ws + WS_OFF);
    int*      bsum = (int*)     (ws + WS_BSUM);
    float*    Wt   = (float*)   (ws + WS_WT);
    int*      pdst = (int*)     (ws + WS_PDST);
    int*      psrc = (int*)     (ws + WS_PSRC);
    int*      csr  = (int*)     (ws + WS_CSR);
    unsigned* xnb  = (unsigned*)(ws + WS_XNB);  // overwrites pdst+psrc AFTER fill_sorted

    hist_src<<<NR * NC, 1024, 0, stream>>>(ei, psrc);
    hist_dst<<<NR * NC, 1024, 0, stream>>>(ei, pdst);
    reduce_both<<<(NN + 255) / 256, 256, 0, stream>>>(psrc, pdst, inv, cnt);
    scan_blocks<<<NB, 1024, 0, stream>>>(cnt, off, bsum);
    scan_chunks<<<(NN + 255) / 256, 256, 0, stream>>>(pdst, off, bsum);
    transpose_w<<<64, 256, 0, stream>>>(W, Wt);
    fill_sorted<<<NR * NC, 1024, 0, stream>>>(ei, pdst, csr);
    scale_kernel<<<(NN * 16 + 255) / 256, 256, 0, stream>>>(x, inv, xnb);
    gather_kernel<<<(NN * 64 + 255) / 256, 256, 0, stream>>>(xnb, inv, off, cnt, csr, out);
    gemm_kernel<<<NN / RPB, 256, 0, stream>>>(out, Wt, b);
}

// Round 7
// 169.120 us; speedup vs baseline: 8.5881x; 1.1694x over previous
//
#include <hip/hip_runtime.h>

#define NN 50000
#define NE 1600000
#define D 128
#define RPB 40       // rows per block in the GEMM epilogue (50000/40 = 1250 blocks)
#define NR 2         // key ranges (node-id partitions)
#define RNG 25000    // NN / NR keys per range
#define NC 32        // src edge chunks (CHUNK = 50000)
#define CHUNK 50000
#define NC2 64       // dst edge chunks (CHUNK2 = 25000)
#define CHUNK2 25000
#define NB 49        // scan blocks = ceil(NN/1024)

// ---- workspace layout (bytes), total 19,879,936 (same as prior passing round) ----
#define WS_INV  0         // float NN
#define WS_CNT  204800    // int NN   (dst degree)
#define WS_OFF  409600    // int NN   (CSR offsets)
#define WS_BSUM 610304    // int NB
#define WS_WT   614400    // float 128*128
#define WS_PDST 679936    // int NR*NC2*RNG = 12.8 MB (dst counts -> absolute bases)
#define WS_PSRC 13479936  // ushort NR*NC*RNG = 3.2 MB (src counts)
#define WS_CSR  16679936  // ushort NE = 3.2 MB
#define WS_XNB  679936    // ushort NN*128 = 12.8 MB, OVERWRITES pdst after fill_sorted

// ---------------- fused: src hist (64 blks) + dst hist (128 blks) + W transpose (16 blks) ----------------
__global__ __launch_bounds__(1024) void fused_pre(const int* __restrict__ ei,
                                                  const float* __restrict__ W,
                                                  unsigned short* __restrict__ psrc,
                                                  int* __restrict__ pdst,
                                                  float* __restrict__ Wt) {
    __shared__ int h[RNG];
    int bid = blockIdx.x;
    if (bid < 64) {
        // src histogram: r = bid>>5, chunk c = bid&31 of CHUNK edges
        int r = bid >> 5, c = bid & 31;
        int lo = r * RNG;
        for (int j = threadIdx.x; j < RNG; j += 1024) h[j] = 0;
        __syncthreads();
        const int* s = ei + c * CHUNK;
        for (int i = threadIdx.x; i < CHUNK; i += 1024) {
            int k = s[i] - lo;
            if ((unsigned)k < RNG) atomicAdd(&h[k], 1);
        }
        __syncthreads();
        unsigned short* p = psrc + (size_t)bid * RNG;
        for (int j = threadIdx.x; j < RNG; j += 1024) p[j] = (unsigned short)h[j];
    } else if (bid < 192) {
        // dst per-chunk counts: b2 in [0,128), r = b2>>6, chunk c = b2&63 of CHUNK2 edges
        int b2 = bid - 64;
        int r = b2 >> 6, c = b2 & 63;
        int lo = r * RNG;
        for (int j = threadIdx.x; j < RNG; j += 1024) h[j] = 0;
        __syncthreads();
        const int* d = ei + NE + c * CHUNK2;
        for (int i = threadIdx.x; i < CHUNK2; i += 1024) {
            int k = d[i] - lo;
            if ((unsigned)k < RNG) atomicAdd(&h[k], 1);
        }
        __syncthreads();
        int* p = pdst + (size_t)b2 * RNG;
        for (int j = threadIdx.x; j < RNG; j += 1024) p[j] = h[j];
    } else {
        // transpose W: 16 blocks x 1024 threads = 16384 elements
        int i = (bid - 192) * 1024 + threadIdx.x;
        int c = i >> 7, k = i & 127;
        Wt[k * D + c] = W[i];
    }
}

// ---------------- inv[k] = rsqrt(src_deg+1); cnt[k] = dst_deg ----------------
__global__ void reduce_both(const unsigned short* __restrict__ psrc,
                            const int* __restrict__ pdst,
                            float* __restrict__ inv, int* __restrict__ cnt) {
    int k = blockIdx.x * blockDim.x + threadIdx.x;
    if (k >= NN) return;
    int r = k / RNG, j = k - r * RNG;
    size_t bs = (size_t)(r * NC) * RNG + j;
    int s = 0;
#pragma unroll 8
    for (int c = 0; c < NC; ++c) s += psrc[bs + (size_t)c * RNG];
    size_t bd = (size_t)(r * NC2) * RNG + j;
    int t = 0;
#pragma unroll 8
    for (int c = 0; c < NC2; ++c) t += pdst[bd + (size_t)c * RNG];
    inv[k] = rsqrtf((float)s + 1.0f);
    cnt[k] = t;
}

// ---------------- phase 1: per-1024-block exclusive scan of cnt ----------------
__global__ __launch_bounds__(1024) void scan_blocks(const int* __restrict__ cnt,
                                                    int* __restrict__ off,
                                                    int* __restrict__ bsum) {
    __shared__ int s[1024];
    int tid = threadIdx.x;
    int i = blockIdx.x * 1024 + tid;
    int v = (i < NN) ? cnt[i] : 0;
    s[tid] = v;
    __syncthreads();
    for (int d = 1; d < 1024; d <<= 1) {
        int t = (tid >= d) ? s[tid - d] : 0;
        __syncthreads();
        s[tid] += t;
        __syncthreads();
    }
    if (i < NN) off[i] = s[tid] - v;  // exclusive within block
    if (tid == 1023) bsum[blockIdx.x] = s[1023];
}

// ---------------- phase 2+3: add block base; pdst counts -> absolute CSR bases ----------------
__global__ void scan_chunks(int* __restrict__ pdst, int* __restrict__ off,
                            const int* __restrict__ bsum) {
    int k = blockIdx.x * blockDim.x + threadIdx.x;
    if (k >= NN) return;
    int bi = k >> 10;
    int top = 0;
#pragma unroll 8
    for (int c = 0; c < bi; ++c) top += bsum[c];  // <=48 L2-broadcast loads
    int run = off[k] + top;
    off[k] = run;  // final CSR offset
    int r = k / RNG, j = k - r * RNG;
    size_t base = (size_t)(r * NC2) * RNG + j;
#pragma unroll 8
    for (int c = 0; c < NC2; ++c) {
        size_t p = base + (size_t)c * RNG;
        int v = pdst[p];
        pdst[p] = run;
        run += v;
    }
}

// ---------------- place edges: LDS cursor atomics only, plain ushort CSR stores ----------------
__global__ __launch_bounds__(1024) void fill_sorted(const int* __restrict__ ei,
                                                    const int* __restrict__ bases,
                                                    unsigned short* __restrict__ csr) {
    __shared__ int cur[RNG];
    int r = blockIdx.x >> 6, c = blockIdx.x & 63;
    int lo = r * RNG;
    const int* bslice = bases + (size_t)blockIdx.x * RNG;
    for (int j = threadIdx.x; j < RNG; j += 1024) cur[j] = bslice[j];
    __syncthreads();
    const int* s = ei + c * CHUNK2;
    const int* d = ei + NE + c * CHUNK2;
    for (int i = threadIdx.x; i < CHUNK2; i += 1024) {
        int kd = d[i] - lo;
        if ((unsigned)kd < RNG) {
            int pos = atomicAdd(&cur[kd], 1);
            csr[pos] = (unsigned short)s[i];
        }
    }
}

// ---------------- xnb[n][c] = bf16_rne(x[n][c] * inv[n]), packed 2/u32 ----------------
__device__ __forceinline__ unsigned bf16_rne(float f) {
    unsigned u = __float_as_uint(f);
    return (u + 0x7fffu + ((u >> 16) & 1u)) >> 16;
}
__global__ void scale_kernel(const float* __restrict__ x, const float* __restrict__ inv,
                             unsigned* __restrict__ xnb4) {
    int i = blockIdx.x * blockDim.x + threadIdx.x;  // 0 .. NN*16-1
    if (i >= NN * 16) return;
    int row = i >> 4;
    float w = inv[row];
    const float4* src = (const float4*)(x + (size_t)i * 8);
    float4 a = src[0], bq = src[1];
    uint4 o;
    o.x = bf16_rne(a.x * w)  | (bf16_rne(a.y * w) << 16);
    o.y = bf16_rne(a.z * w)  | (bf16_rne(a.w * w) << 16);
    o.z = bf16_rne(bq.x * w) | (bf16_rne(bq.y * w) << 16);
    o.w = bf16_rne(bq.z * w) | (bf16_rne(bq.w * w) << 16);
    ((uint4*)xnb4)[i] = o;
}

// ---------------- gather: out[n] = inv[n]*(xnb[n] + sum_s xnb[s]) ----------------
// one wave per node; lanes 0-31 even edges, 32-63 odd; each lane owns 4 cols (8B bf16)
__global__ __launch_bounds__(256) void gather_kernel(const unsigned* __restrict__ xnb,
                                                     const float* __restrict__ inv,
                                                     const int* __restrict__ off,
                                                     const int* __restrict__ cnt,
                                                     const unsigned short* __restrict__ csr,
                                                     float* __restrict__ out) {
    int wid = (blockIdx.x * blockDim.x + threadIdx.x) >> 6;
    if (wid >= NN) return;
    int lane = threadIdx.x & 63;
    int half = lane >> 5;
    int col4 = lane & 31;  // owns cols 4*col4 .. 4*col4+3 (one uint2)

    float ax = 0.f, ay = 0.f, az = 0.f, aw = 0.f;
    const uint2* xb = (const uint2*)xnb;  // 32 uint2 per row
    if (half == 0) {
        uint2 u = xb[(size_t)wid * 32 + col4];
        ax = __uint_as_float(u.x << 16);
        ay = __uint_as_float(u.x & 0xffff0000u);
        az = __uint_as_float(u.y << 16);
        aw = __uint_as_float(u.y & 0xffff0000u);
    }
    int n = cnt[wid];
    const unsigned short* row = csr + off[wid];
    int i = half;
    for (; i + 6 < n; i += 8) {
        int s0 = row[i], s1 = row[i + 2], s2 = row[i + 4], s3 = row[i + 6];
        uint2 u0 = xb[(size_t)s0 * 32 + col4];
        uint2 u1 = xb[(size_t)s1 * 32 + col4];
        uint2 u2 = xb[(size_t)s2 * 32 + col4];
        uint2 u3 = xb[(size_t)s3 * 32 + col4];
        ax += __uint_as_float(u0.x << 16) + __uint_as_float(u1.x << 16)
            + __uint_as_float(u2.x << 16) + __uint_as_float(u3.x << 16);
        ay += __uint_as_float(u0.x & 0xffff0000u) + __uint_as_float(u1.x & 0xffff0000u)
            + __uint_as_float(u2.x & 0xffff0000u) + __uint_as_float(u3.x & 0xffff0000u);
        az += __uint_as_float(u0.y << 16) + __uint_as_float(u1.y << 16)
            + __uint_as_float(u2.y << 16) + __uint_as_float(u3.y << 16);
        aw += __uint_as_float(u0.y & 0xffff0000u) + __uint_as_float(u1.y & 0xffff0000u)
            + __uint_as_float(u2.y & 0xffff0000u) + __uint_as_float(u3.y & 0xffff0000u);
    }
    for (; i < n; i += 2) {
        int s = row[i];
        uint2 u = xb[(size_t)s * 32 + col4];
        ax += __uint_as_float(u.x << 16);
        ay += __uint_as_float(u.x & 0xffff0000u);
        az += __uint_as_float(u.y << 16);
        aw += __uint_as_float(u.y & 0xffff0000u);
    }
    ax += __shfl_xor(ax, 32, 64);
    ay += __shfl_xor(ay, 32, 64);
    az += __shfl_xor(az, 32, 64);
    aw += __shfl_xor(aw, 32, 64);
    if (half == 0) {
        float wn = inv[wid];
        float4 o;
        o.x = ax * wn; o.y = ay * wn; o.z = az * wn; o.w = aw * wn;
        ((float4*)(out + (size_t)wid * D))[col4] = o;
    }
}

// ---------------- out[r][c] = h[r][:] . Wt[:][c] + b[c]  (in-place in io) ----------------
__global__ __launch_bounds__(256) void gemm_kernel(float* io, const float* __restrict__ Wt,
                                                   const float* __restrict__ b) {
    __shared__ float h[RPB][D];
    int r0 = blockIdx.x * RPB;

    const float4* src4 = (const float4*)(io + (size_t)r0 * D);
    for (int t = threadIdx.x; t < RPB * D / 4; t += 256) {
        ((float4*)h)[t] = src4[t];
    }
    __syncthreads();

    int c = threadIdx.x & 127;
    int rh = threadIdx.x >> 7;  // 0 or 1 -> rows rh*20 .. rh*20+19
    float acc[20];
#pragma unroll
    for (int j = 0; j < 20; ++j) acc[j] = 0.0f;

    for (int k0 = 0; k0 < D; k0 += 4) {
        float w0 = Wt[(k0 + 0) * D + c];
        float w1 = Wt[(k0 + 1) * D + c];
        float w2 = Wt[(k0 + 2) * D + c];
        float w3 = Wt[(k0 + 3) * D + c];
#pragma unroll
        for (int j = 0; j < 20; ++j) {
            float4 hv = *(const float4*)&h[rh * 20 + j][k0];  // LDS broadcast, b128
            acc[j] += hv.x * w0 + hv.y * w1 + hv.z * w2 + hv.w * w3;
        }
    }

    float bc = b[c];
#pragma unroll
    for (int j = 0; j < 20; ++j) {
        io[(size_t)(r0 + rh * 20 + j) * D + c] = acc[j] + bc;
    }
}

extern "C" void kernel_launch(void* const* d_in, const int* in_sizes, int n_in,
                              void* d_out, int out_size, void* d_ws, size_t ws_size,
                              hipStream_t stream) {
    const float* x  = (const float*)d_in[0];
    const int*   ei = (const int*)d_in[1];
    const float* W  = (const float*)d_in[2];
    const float* b  = (const float*)d_in[3];
    float* out = (float*)d_out;

    char* ws = (char*)d_ws;
    float*          inv  = (float*)         (ws + WS_INV);
    int*            cnt  = (int*)           (ws + WS_CNT);
    int*            off  = (int*)           (ws + WS_OFF);
    int*            bsum = (int*)           (ws + WS_BSUM);
    float*          Wt   = (float*)         (ws + WS_WT);
    int*            pdst = (int*)           (ws + WS_PDST);
    unsigned short* psrc = (unsigned short*)(ws + WS_PSRC);
    unsigned short* csr  = (unsigned short*)(ws + WS_CSR);
    unsigned*       xnb  = (unsigned*)      (ws + WS_XNB);  // overlays pdst AFTER fill_sorted

    fused_pre<<<208, 1024, 0, stream>>>(ei, W, psrc, pdst, Wt);
    reduce_both<<<(NN + 255) / 256, 256, 0, stream>>>(psrc, pdst, inv, cnt);
    scan_blocks<<<NB, 1024, 0, stream>>>(cnt, off, bsum);
    scan_chunks<<<(NN + 255) / 256, 256, 0, stream>>>(pdst, off, bsum);
    fill_sorted<<<NR * NC2, 1024, 0, stream>>>(ei, pdst, csr);
    scale_kernel<<<(NN * 16 + 255) / 256, 256, 0, stream>>>(x, inv, xnb);
    gather_kernel<<<(NN * 64 + 255) / 256, 256, 0, stream>>>(xnb, inv, off, cnt, csr, out);
    gemm_kernel<<<NN / RPB, 256, 0, stream>>>(out, Wt, b);
}